// Round 3
// baseline (496.009 us; speedup 1.0000x reference)
//
#include <hip/hip_runtime.h>
#include <hip/hip_bf16.h>

// RGCN layer, MI355X (gfx950).
// Stage 1: X[n, r, o] = sum_d nf[n,d] * W[r,d,o]   (bf16 MFMA GEMM, X stored bf16)
// Stage 2: per-block-private counting sort of edges into 782 dst-buckets (64 nodes each).
//          R2 post-mortem: naive CSR scatter write-through'd 64MB (cross-XCD line sharing);
//          private (block,bucket) ranges keep lines block-private -> L2 write-back merges.
// Stage 3: block-per-bucket gather: LDS fp32 accumulator [64 nodes][64 dims], LDS atomics,
//          one coalesced bias+relu output write.
//
// ws: X 102.4MB | rec 8MB | cntT 800KB | offsT 800KB | bsum 3KB  (= 112.0MB total)

#define NN 50000
#define EE 1000000
#define RR 16
#define NBLK 256            // binning blocks
#define EPB 3907            // ceil(EE/NBLK)
#define BSH 6               // 64 nodes per bucket
#define NBUK 782            // ceil(NN/64)
#define NS (NBUK * NBLK)    // 200192 (= 782 scan_a blocks of 256 exactly)

typedef __attribute__((ext_vector_type(8))) short short8;
typedef __attribute__((ext_vector_type(4))) float f32x4;

static __device__ inline unsigned short f2bf(float f) {
  union { __hip_bfloat16 h; unsigned short u; } cv;
  cv.h = __float2bfloat16(f);
  return cv.u;
}
static __device__ inline float bf2f(unsigned short u) {
  union { unsigned int i; float f; } cv;
  cv.i = ((unsigned int)u) << 16;
  return cv.f;
}

// ---------------- Stage 1: dense transform (unchanged) ----------------
__global__ __launch_bounds__(256) void k_gemm(const float* __restrict__ nf,
                                              const float* __restrict__ W,
                                              unsigned short* __restrict__ X) {
  __shared__ __align__(16) unsigned short Wl[64][72];
  const int r = blockIdx.y;
  const int tid = threadIdx.x;
  for (int i = tid; i < 4096; i += 256) {
    Wl[i & 63][i >> 6] = f2bf(W[(r << 12) + i]);  // weight[r,k,o] -> Wl[o][k]
  }
  __syncthreads();
  const int lane = tid & 63;
  const int wv = tid >> 6;
  const int lr = lane & 15, lg = lane >> 4;
  #pragma unroll
  for (int st = 0; st < 4; ++st) {
    const int n0 = (blockIdx.x << 8) + ((wv * 4 + st) << 4);
    short8 a0, a1;
    const int arow = n0 + lr;
    if (arow < NN) {
      const float* ap = nf + arow * 64 + lg * 8;
      float4 v0 = *reinterpret_cast<const float4*>(ap);
      float4 v1 = *reinterpret_cast<const float4*>(ap + 4);
      float4 v2 = *reinterpret_cast<const float4*>(ap + 32);
      float4 v3 = *reinterpret_cast<const float4*>(ap + 36);
      a0 = short8{(short)f2bf(v0.x), (short)f2bf(v0.y), (short)f2bf(v0.z), (short)f2bf(v0.w),
                  (short)f2bf(v1.x), (short)f2bf(v1.y), (short)f2bf(v1.z), (short)f2bf(v1.w)};
      a1 = short8{(short)f2bf(v2.x), (short)f2bf(v2.y), (short)f2bf(v2.z), (short)f2bf(v2.w),
                  (short)f2bf(v3.x), (short)f2bf(v3.y), (short)f2bf(v3.z), (short)f2bf(v3.w)};
    } else {
      a0 = short8{0, 0, 0, 0, 0, 0, 0, 0};
      a1 = a0;
    }
    #pragma unroll
    for (int c = 0; c < 4; ++c) {
      f32x4 acc = {0.f, 0.f, 0.f, 0.f};
      const int o = c * 16 + lr;
      short8 b0 = *reinterpret_cast<const short8*>(&Wl[o][lg * 8]);
      short8 b1 = *reinterpret_cast<const short8*>(&Wl[o][32 + lg * 8]);
      acc = __builtin_amdgcn_mfma_f32_16x16x32_bf16(a0, b0, acc, 0, 0, 0);
      acc = __builtin_amdgcn_mfma_f32_16x16x32_bf16(a1, b1, acc, 0, 0, 0);
      #pragma unroll
      for (int i = 0; i < 4; ++i) {
        const int node = n0 + lg * 4 + i;
        if (node < NN)
          X[(size_t)node * 1024 + (r << 6) + c * 16 + lr] = f2bf(acc[i]);
      }
    }
  }
}

// ---------------- Stage 2: per-block-private counting sort ----------------
__global__ __launch_bounds__(256) void k_hist(const int* __restrict__ edst,
                                              int* __restrict__ cntT) {
  __shared__ int cnt[NBUK];
  const int bl = blockIdx.x, tid = threadIdx.x;
  for (int i = tid; i < NBUK; i += 256) cnt[i] = 0;
  __syncthreads();
  const int e0 = bl * EPB, e1 = min(EE, e0 + EPB);
  for (int e = e0 + tid; e < e1; e += 256) atomicAdd(&cnt[edst[e] >> BSH], 1);
  __syncthreads();
  for (int i = tid; i < NBUK; i += 256) cntT[i * NBLK + bl] = cnt[i];
}

__global__ __launch_bounds__(256) void k_scan_a(const int* __restrict__ cntT,
                                                int* __restrict__ offsT,
                                                int* __restrict__ bsum) {
  __shared__ int s[256];
  const int t = threadIdx.x;
  const int i = blockIdx.x * 256 + t;  // i < NS always (NS = 782*256)
  const int v = cntT[i];
  s[t] = v;
  __syncthreads();
  #pragma unroll
  for (int off = 1; off < 256; off <<= 1) {
    const int x = (t >= off) ? s[t - off] : 0;
    __syncthreads();
    s[t] += x;
    __syncthreads();
  }
  offsT[i] = s[t] - v;  // exclusive within block
  if (t == 255) bsum[blockIdx.x] = s[255];
}

__global__ __launch_bounds__(1024) void k_scan_b(int* __restrict__ bsum) {
  __shared__ int s[1024];
  const int t = threadIdx.x;
  const int v = (t < NBUK) ? bsum[t] : 0;
  s[t] = v;
  __syncthreads();
  #pragma unroll
  for (int off = 1; off < 1024; off <<= 1) {
    const int x = (t >= off) ? s[t - off] : 0;
    __syncthreads();
    s[t] += x;
    __syncthreads();
  }
  if (t < NBUK) bsum[t] = s[t] - v;  // exclusive over scan_a blocks
}

__global__ __launch_bounds__(256) void k_scan_c(int* __restrict__ offsT,
                                                const int* __restrict__ bsum) {
  const int i = blockIdx.x * 256 + threadIdx.x;
  offsT[i] += bsum[blockIdx.x];
}

__global__ __launch_bounds__(256) void k_scatter(const int* __restrict__ esrc,
                                                 const int* __restrict__ edst,
                                                 const int* __restrict__ etyp,
                                                 const float* __restrict__ enorm,
                                                 const int* __restrict__ offsT,
                                                 uint2* __restrict__ rec) {
  __shared__ int cur[NBUK];
  const int bl = blockIdx.x, tid = threadIdx.x;
  for (int i = tid; i < NBUK; i += 256) cur[i] = offsT[i * NBLK + bl];
  __syncthreads();
  const int e0 = bl * EPB, e1 = min(EE, e0 + EPB);
  for (int e = e0 + tid; e < e1; e += 256) {
    const int d = edst[e];
    const int pos = atomicAdd(&cur[d >> BSH], 1);
    // pack: src<<10 | typ<<6 | dstlow  (so r.x>>6 == src*16+typ == X row id)
    rec[pos] = make_uint2(((unsigned)esrc[e] << 10) | ((unsigned)etyp[e] << 6) |
                              (unsigned)(d & 63),
                          __float_as_uint(enorm[e]));
  }
}

// ---------------- Stage 3: block-per-bucket gather + bias + relu ----------------
__global__ __launch_bounds__(256) void k_bgather(const uint2* __restrict__ rec,
                                                 const int* __restrict__ offsT,
                                                 const unsigned short* __restrict__ X,
                                                 const float* __restrict__ bias,
                                                 float* __restrict__ out) {
  __shared__ float acc[64 * 64];  // 16 KB
  const int bu = blockIdx.x, tid = threadIdx.x;
  float4* acc4 = (float4*)acc;
  #pragma unroll
  for (int i = 0; i < 4; ++i) acc4[tid + i * 256] = make_float4(0.f, 0.f, 0.f, 0.f);
  __syncthreads();
  const int start = offsT[bu * NBLK];
  const int end = (bu == NBUK - 1) ? EE : offsT[(bu + 1) * NBLK];
  const int lane = tid & 63, wv = tid >> 6;
  const int total = end - start;
  const int per = (total + 3) >> 2;
  int j = start + wv * per;
  const int je = min(end, j + per);
  // unroll-8: 8 independent 128B X-row loads in flight per wave
  for (; j + 8 <= je; j += 8) {
    unsigned k[8];
    float nm[8], v[8];
    #pragma unroll
    for (int u = 0; u < 8; ++u) {
      const uint2 r = rec[j + u];
      k[u] = r.x;
      nm[u] = __uint_as_float(r.y);
    }
    #pragma unroll
    for (int u = 0; u < 8; ++u) v[u] = bf2f(X[(size_t)(k[u] >> 6) * 64 + lane]);
    #pragma unroll
    for (int u = 0; u < 8; ++u) atomicAdd(&acc[(k[u] & 63u) * 64 + lane], nm[u] * v[u]);
  }
  for (; j < je; ++j) {
    const uint2 r = rec[j];
    atomicAdd(&acc[(r.x & 63u) * 64 + lane],
              __uint_as_float(r.y) * bf2f(X[(size_t)(r.x >> 6) * 64 + lane]));
  }
  __syncthreads();
  const int node0 = bu << BSH;
  const float4* b4 = (const float4*)bias;
  #pragma unroll
  for (int i = 0; i < 4; ++i) {
    const int idx = tid + i * 256;
    const int node = node0 + (idx >> 4);
    if (node < NN) {
      const float4 a = acc4[idx];
      const float4 b = b4[idx & 15];
      float4 o;
      o.x = fmaxf(a.x + b.x, 0.f);
      o.y = fmaxf(a.y + b.y, 0.f);
      o.z = fmaxf(a.z + b.z, 0.f);
      o.w = fmaxf(a.w + b.w, 0.f);
      ((float4*)out)[node0 * 16 + idx] = o;
    }
  }
}

extern "C" void kernel_launch(void* const* d_in, const int* in_sizes, int n_in,
                              void* d_out, int out_size, void* d_ws, size_t ws_size,
                              hipStream_t stream) {
  const float* nf = (const float*)d_in[0];
  const int* esrc = (const int*)d_in[1];
  const int* edst = (const int*)d_in[2];
  const int* etyp = (const int*)d_in[3];
  const float* enorm = (const float*)d_in[4];
  const float* W = (const float*)d_in[5];
  const float* bias = (const float*)d_in[6];
  float* out = (float*)d_out;

  char* ws = (char*)d_ws;
  unsigned short* X = (unsigned short*)ws;        // 102,400,000 B
  uint2* rec = (uint2*)(ws + 102400000);          //   8,000,000 B
  int* cntT = (int*)(ws + 110400000);             //     800,768 B
  int* offsT = (int*)(ws + 111200768);            //     800,768 B
  int* bsum = (int*)(ws + 112001536);             //       3,128 B

  dim3 g1((NN + 255) / 256, RR);
  k_gemm<<<g1, 256, 0, stream>>>(nf, W, X);

  k_hist<<<NBLK, 256, 0, stream>>>(edst, cntT);
  k_scan_a<<<NS / 256, 256, 0, stream>>>(cntT, offsT, bsum);
  k_scan_b<<<1, 1024, 0, stream>>>(bsum);
  k_scan_c<<<NS / 256, 256, 0, stream>>>(offsT, bsum);
  k_scatter<<<NBLK, 256, 0, stream>>>(esrc, edst, etyp, enorm, offsT, rec);

  k_bgather<<<NBUK, 256, 0, stream>>>(rec, offsT, X, bias, out);
}

// Round 4
// 495.553 us; speedup vs baseline: 1.0009x; 1.0009x over previous
//
#include <hip/hip_runtime.h>
#include <hip/hip_bf16.h>

// RGCN layer, MI355X (gfx950).
// Stage 1: X[n, r, o] = sum_d nf[n,d] * W[r,d,o]   (bf16 MFMA GEMM, X stored bf16)
// Stage 2: per-block-private counting sort of edges into 782 dst-buckets (64 nodes each).
//          (R2 post-mortem: shared-line CSR scatter write-through'd 64MB; private
//           (bucket,block) ranges keep lines block-private -> L2 write-back merges.)
// Stage 3: block-per-bucket gather, 512 threads / 8 waves per block (R3 post-mortem:
//          4-wave blocks left the CU latency-exposed at 19% occupancy / 2.6% VALU).
//          LDS fp32 accumulator [64 nodes][64 dims], ds_add_f32, coalesced bias+relu write.
//
// ws: X 102.4MB | rec 8MB | cntT 800KB | offsT 800KB | bsum 3KB  (= 112.0MB total)

#define NN 50000
#define EE 1000000
#define RR 16
#define NBLK 256            // binning blocks
#define EPB 3907            // ceil(EE/NBLK)
#define BSH 6               // 64 nodes per bucket
#define NBUK 782            // ceil(NN/64)
#define NS (NBUK * NBLK)    // 200192 (= 782 scan_a blocks of 256 exactly)

typedef __attribute__((ext_vector_type(8))) short short8;
typedef __attribute__((ext_vector_type(4))) float f32x4;

static __device__ inline unsigned short f2bf(float f) {
  union { __hip_bfloat16 h; unsigned short u; } cv;
  cv.h = __float2bfloat16(f);
  return cv.u;
}
static __device__ inline float bf2f(unsigned short u) {
  union { unsigned int i; float f; } cv;
  cv.i = ((unsigned int)u) << 16;
  return cv.f;
}

// ---------------- Stage 1: dense transform (unchanged) ----------------
__global__ __launch_bounds__(256) void k_gemm(const float* __restrict__ nf,
                                              const float* __restrict__ W,
                                              unsigned short* __restrict__ X) {
  __shared__ __align__(16) unsigned short Wl[64][72];
  const int r = blockIdx.y;
  const int tid = threadIdx.x;
  for (int i = tid; i < 4096; i += 256) {
    Wl[i & 63][i >> 6] = f2bf(W[(r << 12) + i]);  // weight[r,k,o] -> Wl[o][k]
  }
  __syncthreads();
  const int lane = tid & 63;
  const int wv = tid >> 6;
  const int lr = lane & 15, lg = lane >> 4;
  #pragma unroll
  for (int st = 0; st < 4; ++st) {
    const int n0 = (blockIdx.x << 8) + ((wv * 4 + st) << 4);
    short8 a0, a1;
    const int arow = n0 + lr;
    if (arow < NN) {
      const float* ap = nf + arow * 64 + lg * 8;
      float4 v0 = *reinterpret_cast<const float4*>(ap);
      float4 v1 = *reinterpret_cast<const float4*>(ap + 4);
      float4 v2 = *reinterpret_cast<const float4*>(ap + 32);
      float4 v3 = *reinterpret_cast<const float4*>(ap + 36);
      a0 = short8{(short)f2bf(v0.x), (short)f2bf(v0.y), (short)f2bf(v0.z), (short)f2bf(v0.w),
                  (short)f2bf(v1.x), (short)f2bf(v1.y), (short)f2bf(v1.z), (short)f2bf(v1.w)};
      a1 = short8{(short)f2bf(v2.x), (short)f2bf(v2.y), (short)f2bf(v2.z), (short)f2bf(v2.w),
                  (short)f2bf(v3.x), (short)f2bf(v3.y), (short)f2bf(v3.z), (short)f2bf(v3.w)};
    } else {
      a0 = short8{0, 0, 0, 0, 0, 0, 0, 0};
      a1 = a0;
    }
    #pragma unroll
    for (int c = 0; c < 4; ++c) {
      f32x4 acc = {0.f, 0.f, 0.f, 0.f};
      const int o = c * 16 + lr;
      short8 b0 = *reinterpret_cast<const short8*>(&Wl[o][lg * 8]);
      short8 b1 = *reinterpret_cast<const short8*>(&Wl[o][32 + lg * 8]);
      acc = __builtin_amdgcn_mfma_f32_16x16x32_bf16(a0, b0, acc, 0, 0, 0);
      acc = __builtin_amdgcn_mfma_f32_16x16x32_bf16(a1, b1, acc, 0, 0, 0);
      #pragma unroll
      for (int i = 0; i < 4; ++i) {
        const int node = n0 + lg * 4 + i;
        if (node < NN)
          X[(size_t)node * 1024 + (r << 6) + c * 16 + lr] = f2bf(acc[i]);
      }
    }
  }
}

// ---------------- Stage 2: per-block-private counting sort ----------------
__global__ __launch_bounds__(256) void k_hist(const int* __restrict__ edst,
                                              int* __restrict__ cntT) {
  __shared__ int cnt[NBUK];
  const int bl = blockIdx.x, tid = threadIdx.x;
  for (int i = tid; i < NBUK; i += 256) cnt[i] = 0;
  __syncthreads();
  const int e0 = bl * EPB, e1 = min(EE, e0 + EPB);
  for (int e = e0 + tid; e < e1; e += 256) atomicAdd(&cnt[edst[e] >> BSH], 1);
  __syncthreads();
  for (int i = tid; i < NBUK; i += 256) cntT[i * NBLK + bl] = cnt[i];
}

__global__ __launch_bounds__(256) void k_scan_a(const int* __restrict__ cntT,
                                                int* __restrict__ offsT,
                                                int* __restrict__ bsum) {
  __shared__ int s[256];
  const int t = threadIdx.x;
  const int i = blockIdx.x * 256 + t;  // i < NS always
  const int v = cntT[i];
  s[t] = v;
  __syncthreads();
  #pragma unroll
  for (int off = 1; off < 256; off <<= 1) {
    const int x = (t >= off) ? s[t - off] : 0;
    __syncthreads();
    s[t] += x;
    __syncthreads();
  }
  offsT[i] = s[t] - v;  // exclusive within block
  if (t == 255) bsum[blockIdx.x] = s[255];
}

__global__ __launch_bounds__(1024) void k_scan_b(int* __restrict__ bsum) {
  __shared__ int s[1024];
  const int t = threadIdx.x;
  const int v = (t < NBUK) ? bsum[t] : 0;
  s[t] = v;
  __syncthreads();
  #pragma unroll
  for (int off = 1; off < 1024; off <<= 1) {
    const int x = (t >= off) ? s[t - off] : 0;
    __syncthreads();
    s[t] += x;
    __syncthreads();
  }
  if (t < NBUK) bsum[t] = s[t] - v;  // exclusive over scan_a blocks
}

__global__ __launch_bounds__(256) void k_scan_c(int* __restrict__ offsT,
                                                const int* __restrict__ bsum) {
  const int i = blockIdx.x * 256 + threadIdx.x;
  offsT[i] += bsum[blockIdx.x];
}

__global__ __launch_bounds__(256) void k_scatter(const int* __restrict__ esrc,
                                                 const int* __restrict__ edst,
                                                 const int* __restrict__ etyp,
                                                 const float* __restrict__ enorm,
                                                 const int* __restrict__ offsT,
                                                 uint2* __restrict__ rec) {
  __shared__ int cur[NBUK];
  const int bl = blockIdx.x, tid = threadIdx.x;
  for (int i = tid; i < NBUK; i += 256) cur[i] = offsT[i * NBLK + bl];
  __syncthreads();
  const int e0 = bl * EPB, e1 = min(EE, e0 + EPB);
  for (int e = e0 + tid; e < e1; e += 256) {
    const int d = edst[e];
    const int pos = atomicAdd(&cur[d >> BSH], 1);
    // pack: src<<10 | typ<<6 | dstlow  (so r.x>>6 == src*16+typ == X row id)
    rec[pos] = make_uint2(((unsigned)esrc[e] << 10) | ((unsigned)etyp[e] << 6) |
                              (unsigned)(d & 63),
                          __float_as_uint(enorm[e]));
  }
}

// ---------------- Stage 3: block-per-bucket gather + bias + relu ----------------
__global__ __launch_bounds__(512) void k_bgather(const uint2* __restrict__ rec,
                                                 const int* __restrict__ offsT,
                                                 const unsigned short* __restrict__ X,
                                                 const float* __restrict__ bias,
                                                 float* __restrict__ out) {
  __shared__ float acc[64 * 64];  // 16 KB
  const int bu = blockIdx.x, tid = threadIdx.x;
  float4* acc4 = (float4*)acc;
  #pragma unroll
  for (int i = 0; i < 2; ++i) acc4[tid + i * 512] = make_float4(0.f, 0.f, 0.f, 0.f);
  __syncthreads();
  const int start = offsT[bu * NBLK];
  const int end = (bu == NBUK - 1) ? EE : offsT[(bu + 1) * NBLK];
  const int lane = tid & 63, wv = tid >> 6;  // 8 waves per block
  const int total = end - start;
  const int per = (total + 7) >> 3;
  int j = start + wv * per;
  const int je = min(end, j + per);
  // unroll-8: all 8 rec loads, then all 8 X-row loads, then 8 LDS adds
  for (; j + 8 <= je; j += 8) {
    unsigned k[8];
    float nm[8], v[8];
    #pragma unroll
    for (int u = 0; u < 8; ++u) {
      const uint2 r = rec[j + u];
      k[u] = r.x;
      nm[u] = __uint_as_float(r.y);
    }
    #pragma unroll
    for (int u = 0; u < 8; ++u) v[u] = bf2f(X[(size_t)(k[u] >> 6) * 64 + lane]);
    #pragma unroll
    for (int u = 0; u < 8; ++u) atomicAdd(&acc[(k[u] & 63u) * 64 + lane], nm[u] * v[u]);
  }
  for (; j < je; ++j) {
    const uint2 r = rec[j];
    atomicAdd(&acc[(r.x & 63u) * 64 + lane],
              __uint_as_float(r.y) * bf2f(X[(size_t)(r.x >> 6) * 64 + lane]));
  }
  __syncthreads();
  const int node0 = bu << BSH;
  const float4* b4 = (const float4*)bias;
  #pragma unroll
  for (int i = 0; i < 2; ++i) {
    const int idx = tid + i * 512;
    const int node = node0 + (idx >> 4);
    if (node < NN) {
      const float4 a = acc4[idx];
      const float4 b = b4[idx & 15];
      float4 o;
      o.x = fmaxf(a.x + b.x, 0.f);
      o.y = fmaxf(a.y + b.y, 0.f);
      o.z = fmaxf(a.z + b.z, 0.f);
      o.w = fmaxf(a.w + b.w, 0.f);
      ((float4*)out)[node0 * 16 + idx] = o;
    }
  }
}

extern "C" void kernel_launch(void* const* d_in, const int* in_sizes, int n_in,
                              void* d_out, int out_size, void* d_ws, size_t ws_size,
                              hipStream_t stream) {
  const float* nf = (const float*)d_in[0];
  const int* esrc = (const int*)d_in[1];
  const int* edst = (const int*)d_in[2];
  const int* etyp = (const int*)d_in[3];
  const float* enorm = (const float*)d_in[4];
  const float* W = (const float*)d_in[5];
  const float* bias = (const float*)d_in[6];
  float* out = (float*)d_out;

  char* ws = (char*)d_ws;
  unsigned short* X = (unsigned short*)ws;        // 102,400,000 B
  uint2* rec = (uint2*)(ws + 102400000);          //   8,000,000 B
  int* cntT = (int*)(ws + 110400000);             //     800,768 B
  int* offsT = (int*)(ws + 111200768);            //     800,768 B
  int* bsum = (int*)(ws + 112001536);             //       3,128 B

  dim3 g1((NN + 255) / 256, RR);
  k_gemm<<<g1, 256, 0, stream>>>(nf, W, X);

  k_hist<<<NBLK, 256, 0, stream>>>(edst, cntT);
  k_scan_a<<<NS / 256, 256, 0, stream>>>(cntT, offsT, bsum);
  k_scan_b<<<1, 1024, 0, stream>>>(bsum);
  k_scan_c<<<NS / 256, 256, 0, stream>>>(offsT, bsum);
  k_scatter<<<NBLK, 256, 0, stream>>>(esrc, edst, etyp, enorm, offsT, rec);

  k_bgather<<<NBUK, 512, 0, stream>>>(rec, offsT, X, bias, out);
}

// Round 5
// 125.278 us; speedup vs baseline: 3.9593x; 3.9556x over previous
//
#include <hip/hip_runtime.h>
#include <hip/hip_bf16.h>

// RGCN layer, MI355X (gfx950).
// Stage 1: X[n, r, o] = sum_d nf[n,d] * W[r,d,o]   (bf16 MFMA GEMM, X stored bf16)
// Stage 2a: per-block-private counting sort of edges into 782 dst-buckets (64 nodes).
// Stage 2b: k_nsort — within each bucket, LDS-staged counting sort by exact dst node
//           (in place), emitting per-node CSR offsets noffs.
// Stage 3: k_ngather — wave-per-node REGISTER accumulation (R4 post-mortem: LDS float
//          atomicAdd is a CAS loop; 428us invariant to occupancy. No atomics here.)
//
// ws: X 102.4MB | rec 8MB | cntT 800KB | offsT 800KB | bsum 3KB | noffs 200KB (=112.2MB)

#define NN 50000
#define EE 1000000
#define RR 16
#define NBLK 256            // binning blocks
#define EPB 3907            // ceil(EE/NBLK)
#define BSH 6               // 64 nodes per bucket
#define NBUK 782            // ceil(NN/64)
#define NS (NBUK * NBLK)    // 200192 (= 782 scan_a blocks of 256 exactly)
#define SCAP 2048           // k_nsort LDS record capacity (mean 1279, +21 sigma)

typedef __attribute__((ext_vector_type(8))) short short8;
typedef __attribute__((ext_vector_type(4))) float f32x4;

static __device__ inline unsigned short f2bf(float f) {
  union { __hip_bfloat16 h; unsigned short u; } cv;
  cv.h = __float2bfloat16(f);
  return cv.u;
}
static __device__ inline float bf2f(unsigned short u) {
  union { unsigned int i; float f; } cv;
  cv.i = ((unsigned int)u) << 16;
  return cv.f;
}

// ---------------- Stage 1: dense transform (unchanged) ----------------
__global__ __launch_bounds__(256) void k_gemm(const float* __restrict__ nf,
                                              const float* __restrict__ W,
                                              unsigned short* __restrict__ X) {
  __shared__ __align__(16) unsigned short Wl[64][72];
  const int r = blockIdx.y;
  const int tid = threadIdx.x;
  for (int i = tid; i < 4096; i += 256) {
    Wl[i & 63][i >> 6] = f2bf(W[(r << 12) + i]);  // weight[r,k,o] -> Wl[o][k]
  }
  __syncthreads();
  const int lane = tid & 63;
  const int wv = tid >> 6;
  const int lr = lane & 15, lg = lane >> 4;
  #pragma unroll
  for (int st = 0; st < 4; ++st) {
    const int n0 = (blockIdx.x << 8) + ((wv * 4 + st) << 4);
    short8 a0, a1;
    const int arow = n0 + lr;
    if (arow < NN) {
      const float* ap = nf + arow * 64 + lg * 8;
      float4 v0 = *reinterpret_cast<const float4*>(ap);
      float4 v1 = *reinterpret_cast<const float4*>(ap + 4);
      float4 v2 = *reinterpret_cast<const float4*>(ap + 32);
      float4 v3 = *reinterpret_cast<const float4*>(ap + 36);
      a0 = short8{(short)f2bf(v0.x), (short)f2bf(v0.y), (short)f2bf(v0.z), (short)f2bf(v0.w),
                  (short)f2bf(v1.x), (short)f2bf(v1.y), (short)f2bf(v1.z), (short)f2bf(v1.w)};
      a1 = short8{(short)f2bf(v2.x), (short)f2bf(v2.y), (short)f2bf(v2.z), (short)f2bf(v2.w),
                  (short)f2bf(v3.x), (short)f2bf(v3.y), (short)f2bf(v3.z), (short)f2bf(v3.w)};
    } else {
      a0 = short8{0, 0, 0, 0, 0, 0, 0, 0};
      a1 = a0;
    }
    #pragma unroll
    for (int c = 0; c < 4; ++c) {
      f32x4 acc = {0.f, 0.f, 0.f, 0.f};
      const int o = c * 16 + lr;
      short8 b0 = *reinterpret_cast<const short8*>(&Wl[o][lg * 8]);
      short8 b1 = *reinterpret_cast<const short8*>(&Wl[o][32 + lg * 8]);
      acc = __builtin_amdgcn_mfma_f32_16x16x32_bf16(a0, b0, acc, 0, 0, 0);
      acc = __builtin_amdgcn_mfma_f32_16x16x32_bf16(a1, b1, acc, 0, 0, 0);
      #pragma unroll
      for (int i = 0; i < 4; ++i) {
        const int node = n0 + lg * 4 + i;
        if (node < NN)
          X[(size_t)node * 1024 + (r << 6) + c * 16 + lr] = f2bf(acc[i]);
      }
    }
  }
}

// ---------------- Stage 2a: per-block-private bucket sort ----------------
__global__ __launch_bounds__(256) void k_hist(const int* __restrict__ edst,
                                              int* __restrict__ cntT) {
  __shared__ int cnt[NBUK];
  const int bl = blockIdx.x, tid = threadIdx.x;
  for (int i = tid; i < NBUK; i += 256) cnt[i] = 0;
  __syncthreads();
  const int e0 = bl * EPB, e1 = min(EE, e0 + EPB);
  for (int e = e0 + tid; e < e1; e += 256) atomicAdd(&cnt[edst[e] >> BSH], 1);
  __syncthreads();
  for (int i = tid; i < NBUK; i += 256) cntT[i * NBLK + bl] = cnt[i];
}

__global__ __launch_bounds__(256) void k_scan_a(const int* __restrict__ cntT,
                                                int* __restrict__ offsT,
                                                int* __restrict__ bsum) {
  __shared__ int s[256];
  const int t = threadIdx.x;
  const int i = blockIdx.x * 256 + t;  // i < NS always
  const int v = cntT[i];
  s[t] = v;
  __syncthreads();
  #pragma unroll
  for (int off = 1; off < 256; off <<= 1) {
    const int x = (t >= off) ? s[t - off] : 0;
    __syncthreads();
    s[t] += x;
    __syncthreads();
  }
  offsT[i] = s[t] - v;  // exclusive within block
  if (t == 255) bsum[blockIdx.x] = s[255];
}

__global__ __launch_bounds__(1024) void k_scan_b(int* __restrict__ bsum) {
  __shared__ int s[1024];
  const int t = threadIdx.x;
  const int v = (t < NBUK) ? bsum[t] : 0;
  s[t] = v;
  __syncthreads();
  #pragma unroll
  for (int off = 1; off < 1024; off <<= 1) {
    const int x = (t >= off) ? s[t - off] : 0;
    __syncthreads();
    s[t] += x;
    __syncthreads();
  }
  if (t < NBUK) bsum[t] = s[t] - v;  // exclusive over scan_a blocks
}

__global__ __launch_bounds__(256) void k_scan_c(int* __restrict__ offsT,
                                                const int* __restrict__ bsum) {
  const int i = blockIdx.x * 256 + threadIdx.x;
  offsT[i] += bsum[blockIdx.x];
}

__global__ __launch_bounds__(256) void k_scatter(const int* __restrict__ esrc,
                                                 const int* __restrict__ edst,
                                                 const int* __restrict__ etyp,
                                                 const float* __restrict__ enorm,
                                                 const int* __restrict__ offsT,
                                                 uint2* __restrict__ rec) {
  __shared__ int cur[NBUK];
  const int bl = blockIdx.x, tid = threadIdx.x;
  for (int i = tid; i < NBUK; i += 256) cur[i] = offsT[i * NBLK + bl];
  __syncthreads();
  const int e0 = bl * EPB, e1 = min(EE, e0 + EPB);
  for (int e = e0 + tid; e < e1; e += 256) {
    const int d = edst[e];
    const int pos = atomicAdd(&cur[d >> BSH], 1);
    // pack: src<<10 | typ<<6 | dstlow  (so r.x>>6 == src*16+typ == X row id)
    rec[pos] = make_uint2(((unsigned)esrc[e] << 10) | ((unsigned)etyp[e] << 6) |
                              (unsigned)(d & 63),
                          __float_as_uint(enorm[e]));
  }
}

// ---------------- Stage 2b: in-bucket sort by exact dst node (in place) ----------------
__global__ __launch_bounds__(256) void k_nsort(const int* __restrict__ offsT,
                                               uint2* __restrict__ rec,
                                               int* __restrict__ noffs) {
  __shared__ uint2 sbuf[SCAP];  // 16 KB
  __shared__ int cnt[64], cur[64];
  const int bu = blockIdx.x, tid = threadIdx.x;
  const int s = offsT[bu * NBLK];
  const int e = (bu == NBUK - 1) ? EE : offsT[(bu + 1) * NBLK];
  const int n = e - s;
  if (tid < 64) cnt[tid] = 0;
  __syncthreads();
  if (n > SCAP) {  // ~impossible (+21 sigma) overflow: leave unsorted, mark for slow gather
    if (tid < 64) noffs[(bu << BSH) + tid] = -1;
    return;
  }
  for (int i = tid; i < n; i += 256) {
    const uint2 r = rec[s + i];
    sbuf[i] = r;
    atomicAdd(&cnt[r.x & 63u], 1);  // int LDS atomic: native ds_add_u32
  }
  __syncthreads();
  if (tid < 64) {  // wave shfl exclusive scan of 64 bins
    const int v = cnt[tid];
    int x = v;
    #pragma unroll
    for (int off = 1; off < 64; off <<= 1) {
      const int t = __shfl_up(x, off, 64);
      if (tid >= off) x += t;
    }
    cur[tid] = x - v;
    noffs[(bu << BSH) + tid] = s + x - v;
  }
  __syncthreads();
  for (int i = tid; i < n; i += 256) {
    const uint2 r = sbuf[i];
    const int pos = atomicAdd(&cur[r.x & 63u], 1);
    rec[s + pos] = r;  // in place: all reads completed before barrier above
  }
}

// ---------------- Stage 3: wave-per-node register gather + bias + relu ----------------
__global__ __launch_bounds__(256) void k_ngather(const uint2* __restrict__ rec,
                                                 const int* __restrict__ noffs,
                                                 const int* __restrict__ offsT,
                                                 const unsigned short* __restrict__ X,
                                                 const float* __restrict__ bias,
                                                 float* __restrict__ out) {
  const int w = (int)((blockIdx.x * 256 + threadIdx.x) >> 6);  // node id
  const int lane = threadIdx.x & 63;
  if (w >= NN) return;
  const int bu = w >> BSH;
  float a0 = 0.f, a1 = 0.f, a2 = 0.f, a3 = 0.f;
  const int jb = noffs[w];
  if (jb >= 0) {
    const int bend = (bu == NBUK - 1) ? EE : offsT[(bu + 1) * NBLK];
    const int je = ((w & 63) == 63) ? bend : noffs[w + 1];
    int j = jb;
    for (; j + 4 <= je; j += 4) {
      const uint2 r0 = rec[j], r1 = rec[j + 1], r2 = rec[j + 2], r3 = rec[j + 3];
      const float x0 = bf2f(X[(size_t)(r0.x >> 6) * 64 + lane]);
      const float x1 = bf2f(X[(size_t)(r1.x >> 6) * 64 + lane]);
      const float x2 = bf2f(X[(size_t)(r2.x >> 6) * 64 + lane]);
      const float x3 = bf2f(X[(size_t)(r3.x >> 6) * 64 + lane]);
      a0 = fmaf(__uint_as_float(r0.y), x0, a0);
      a1 = fmaf(__uint_as_float(r1.y), x1, a1);
      a2 = fmaf(__uint_as_float(r2.y), x2, a2);
      a3 = fmaf(__uint_as_float(r3.y), x3, a3);
    }
    for (; j < je; ++j) {
      const uint2 r = rec[j];
      a0 = fmaf(__uint_as_float(r.y), bf2f(X[(size_t)(r.x >> 6) * 64 + lane]), a0);
    }
  } else {
    // oversized-bucket fallback: filter-scan the whole (unsorted) bucket
    const int s = offsT[bu * NBLK];
    const int e = (bu == NBUK - 1) ? EE : offsT[(bu + 1) * NBLK];
    const unsigned dl = (unsigned)(w & 63);
    for (int j = s; j < e; ++j) {
      const uint2 r = rec[j];
      if ((r.x & 63u) == dl)
        a0 = fmaf(__uint_as_float(r.y), bf2f(X[(size_t)(r.x >> 6) * 64 + lane]), a0);
    }
  }
  const float a = (a0 + a1) + (a2 + a3) + bias[lane];
  out[(size_t)w * 64 + lane] = fmaxf(a, 0.f);
}

extern "C" void kernel_launch(void* const* d_in, const int* in_sizes, int n_in,
                              void* d_out, int out_size, void* d_ws, size_t ws_size,
                              hipStream_t stream) {
  const float* nf = (const float*)d_in[0];
  const int* esrc = (const int*)d_in[1];
  const int* edst = (const int*)d_in[2];
  const int* etyp = (const int*)d_in[3];
  const float* enorm = (const float*)d_in[4];
  const float* W = (const float*)d_in[5];
  const float* bias = (const float*)d_in[6];
  float* out = (float*)d_out;

  char* ws = (char*)d_ws;
  unsigned short* X = (unsigned short*)ws;        // 102,400,000 B
  uint2* rec = (uint2*)(ws + 102400000);          //   8,000,000 B
  int* cntT = (int*)(ws + 110400000);             //     800,768 B
  int* offsT = (int*)(ws + 111200768);            //     800,768 B
  int* bsum = (int*)(ws + 112001536);             //       3,128 B
  int* noffs = (int*)(ws + 112004664);            //     200,192 B

  dim3 g1((NN + 255) / 256, RR);
  k_gemm<<<g1, 256, 0, stream>>>(nf, W, X);

  k_hist<<<NBLK, 256, 0, stream>>>(edst, cntT);
  k_scan_a<<<NS / 256, 256, 0, stream>>>(cntT, offsT, bsum);
  k_scan_b<<<1, 1024, 0, stream>>>(bsum);
  k_scan_c<<<NS / 256, 256, 0, stream>>>(offsT, bsum);
  k_scatter<<<NBLK, 256, 0, stream>>>(esrc, edst, etyp, enorm, offsT, rec);
  k_nsort<<<NBUK, 256, 0, stream>>>(offsT, rec, noffs);

  k_ngather<<<(NN * 64 + 255) / 256, 256, 0, stream>>>(rec, noffs, offsT, X, bias, out);
}